// Round 4
// baseline (383.309 us; speedup 1.0000x reference)
//
#include <hip/hip_runtime.h>

// Fusin_Dice_rank: fused 2-ch softmax + dice + top-30 rank hinge.
// Keys: order-preserving u32 ord(d), d = x1-x0 (monotone with p=sigmoid(d)).
// t is binary -> each element feeds exactly ONE of the two top-k problems:
//   A (t==0): key o=ordf(d); B (t==1): key ~o = ordf(-d).
// passA: streaming pass; dice partials; STATIC-threshold filter (d>=3.5,
//   ~874 passers/sample expected) emitting straight to per-sample global
//   candidate buffers via device atomics. No histogram, 1 barrier.
// passB (32 blocks): per-sample radix top-30 over ~874 LDS-resident
//   candidates + deterministic rank-sort + hinge + dice finalize; exact
//   global-argmax fallback if candidate count < 30 or > CAP (never on this
//   data, required for arbitrary-input correctness). Last finishing block
//   reduces the 32 samples -> out.

#define N_ELEM (512 * 512)
#define B_SAMPLES 32
#define CHUNK 4096
#define BLOCKS_PER_S 64
#define TOPK 30
#define CAP 4096
#define BINS 1024
// ordf(3.5f): 3.5f = 0x40600000, positive -> | 0x80000000
#define THR_KEY 0xC0600000u

// ws layout in 4-byte units
#define PART_OFF 0                                   // [32][64][3] f32
#define CTR_OFF (PART_OFF + B_SAMPLES * BLOCKS_PER_S * 3)  // 6144
#define CTRA_OFF (CTR_OFF)                           // [32] u32
#define CTRB_OFF (CTR_OFF + B_SAMPLES)               // [32] u32
#define DONE_OFF (CTR_OFF + 2 * B_SAMPLES)           // [1] u32
#define CANDA_OFF (CTR_OFF + 128)                    // [32][CAP] u32
#define CANDB_OFF (CANDA_OFF + B_SAMPLES * CAP)
#define SAMP_OFF (CANDB_OFF + B_SAMPLES * CAP)       // [32][2] f32

__device__ __forceinline__ unsigned ordf(float f) {
    unsigned u = __float_as_uint(f);
    return (u & 0x80000000u) ? ~u : (u | 0x80000000u);
}

__device__ __forceinline__ float invord_sigmoid(unsigned u) {
    // value = sigmoid(f) where u = ordf(f); u==0 placeholder -> exact 0.0
    if (u == 0u) return 0.0f;
    unsigned b = (u & 0x80000000u) ? (u ^ 0x80000000u) : ~u;
    float f = __uint_as_float(b);
    return 1.0f / (1.0f + __expf(-f));
}

__device__ __forceinline__ unsigned long long shflxor_u64(unsigned long long v, int off) {
    unsigned lo = (unsigned)v, hi = (unsigned)(v >> 32);
    lo = __shfl_xor(lo, off, 64);
    hi = __shfl_xor(hi, off, 64);
    return ((unsigned long long)hi << 32) | lo;
}

__global__ __launch_bounds__(256) void passA(const float* __restrict__ pred,
                                             const float* __restrict__ tgt,
                                             float* __restrict__ wsf) {
    unsigned* wsu = (unsigned*)wsf;
    const int s = blockIdx.x >> 6, c = blockIdx.x & 63;
    const int tid = threadIdx.x, lane = tid & 63, wid = tid >> 6;

    const float* x0p = pred + (size_t)s * 2 * N_ELEM + (size_t)c * CHUNK;
    const float* x1p = x0p + N_ELEM;
    const float* tp  = tgt + (size_t)s * N_ELEM + (size_t)c * CHUNK;

    unsigned o[16];
    unsigned tmask = 0u;
    float sp = 0.f, spt = 0.f;

#pragma unroll
    for (int j = 0; j < 4; ++j) {
        float4 X0 = ((const float4*)x0p)[j * 256 + tid];
        float4 X1 = ((const float4*)x1p)[j * 256 + tid];
        float4 T  = ((const float4*)tp )[j * 256 + tid];
#define PROC(q, xx0, xx1, tt)                                  \
        {                                                      \
            float d = (xx1) - (xx0);                           \
            float p = 1.0f / (1.0f + __expf(-d));              \
            sp += p; spt = fmaf(p, (tt), spt);                 \
            o[j * 4 + (q)] = ordf(d);                          \
            if ((tt) != 0.0f) tmask |= 1u << (j * 4 + (q));    \
        }
        PROC(0, X0.x, X1.x, T.x)
        PROC(1, X0.y, X1.y, T.y)
        PROC(2, X0.z, X1.z, T.z)
        PROC(3, X0.w, X1.w, T.w)
#undef PROC
    }
    float st = (float)__popc(tmask);

    __shared__ float red[12];

    // dice partial sums
    for (int off = 32; off; off >>= 1) {
        sp  += __shfl_xor(sp, off, 64);
        st  += __shfl_xor(st, off, 64);
        spt += __shfl_xor(spt, off, 64);
    }
    if (lane == 0) { red[wid * 3] = sp; red[wid * 3 + 1] = st; red[wid * 3 + 2] = spt; }

    // static-threshold emit (rare: ~0.7% of elements pass)
    unsigned* candA = wsu + CANDA_OFF + (size_t)s * CAP;
    unsigned* candB = wsu + CANDB_OFF + (size_t)s * CAP;
#pragma unroll
    for (int e = 0; e < 16; ++e) {
        unsigned key = o[e];
        if ((tmask >> e) & 1u) {
            unsigned kb = ~key;                       // == ordf(-d)
            if (kb >= THR_KEY) {
                unsigned pos = atomicAdd(&wsu[CTRB_OFF + s], 1u);
                if (pos < CAP) candB[pos] = kb;
            }
        } else {
            if (key >= THR_KEY) {
                unsigned pos = atomicAdd(&wsu[CTRA_OFF + s], 1u);
                if (pos < CAP) candA[pos] = key;
            }
        }
    }

    __syncthreads();
    if (tid == 0) {
        float a = 0.f, b = 0.f, cc = 0.f;
#pragma unroll
        for (int w = 0; w < 4; ++w) { a += red[w * 3]; b += red[w * 3 + 1]; cc += red[w * 3 + 2]; }
        float* part = wsf + PART_OFF + (size_t)(s * BLOCKS_PER_S + c) * 3;
        part[0] = a; part[1] = b; part[2] = cc;
    }
}

// Exact top-30 fallback: 30 rounds of block argmax over the full sample,
// recomputing keys from inputs. Only runs if the threshold filter failed
// (count < 30 or > CAP) — unreachable on benchmark data, required for
// arbitrary-input correctness. Writes descending values to dst[0..29].
__device__ void fallback30(const float* __restrict__ x0p, const float* __restrict__ x1p,
                           const float* __restrict__ tp, int isB, float* dst,
                           int tid, int lane, int wid, unsigned long long* sred) {
    unsigned long long prev = ~0ull;
    for (int r = 0; r < TOPK; ++r) {
        unsigned long long best = 0ull;
        for (int e = tid; e < N_ELEM; e += 256) {
            float d = x1p[e] - x0p[e];
            float t = tp[e];
            unsigned key;
            if (isB) key = (t != 0.0f) ? ordf(-d) : 0u;
            else     key = (t == 0.0f) ? ordf(d) : 0u;
            unsigned long long pk = ((unsigned long long)key << 18) | (unsigned)e;
            if (pk < prev && pk > best) best = pk;
        }
        for (int off = 32; off; off >>= 1) {
            unsigned long long v = shflxor_u64(best, off);
            if (v > best) best = v;
        }
        if (lane == 0) sred[wid] = best;
        __syncthreads();
        unsigned long long b0 = sred[0];
#pragma unroll
        for (int w = 1; w < 4; ++w) if (sred[w] > b0) b0 = sred[w];
        __syncthreads();
        if (tid == 0) dst[r] = invord_sigmoid((unsigned)(b0 >> 18));
        prev = b0;
    }
}

__global__ __launch_bounds__(256) void passB(const float* __restrict__ pred,
                                             const float* __restrict__ tgt,
                                             float* __restrict__ wsf,
                                             float* __restrict__ out) {
    unsigned* wsu = (unsigned*)wsf;
    const int s = blockIdx.x;
    const int tid = threadIdx.x, lane = tid & 63, wid = tid >> 6;

    __shared__ unsigned L[CAP];      // 16 KB
    __shared__ int hist[BINS];       // 4 KB
    __shared__ int wtot[4];
    __shared__ int shBt, shChi, shCntBt, shK, shR, shResolved, shDone;
    __shared__ unsigned R[TOPK];
    __shared__ float ntop[TOPK], pv[TOPK], fred[8];
    __shared__ unsigned long long sred[4];

    // wave 0: dice sums over the 64 chunk partials
    if (wid == 0) {
        const float* part = wsf + PART_OFF + (size_t)(s * BLOCKS_PER_S + lane) * 3;
        float sp = part[0], st = part[1], spt = part[2];
        for (int off = 32; off; off >>= 1) {
            sp  += __shfl_xor(sp, off, 64);
            st  += __shfl_xor(st, off, 64);
            spt += __shfl_xor(spt, off, 64);
        }
        if (lane == 0) { fred[0] = sp; fred[1] = st; fred[2] = spt; }
    }

    for (int arr = 0; arr < 2; ++arr) {
        const int n = (int)wsu[(arr ? CTRB_OFF : CTRA_OFF) + s];
        float* dst = arr ? pv : ntop;

        if (n < TOPK || n > CAP) {
            // exact fallback (block-uniform branch)
            const float* x0p = pred + (size_t)s * 2 * N_ELEM;
            fallback30(x0p, x0p + N_ELEM, tgt + (size_t)s * N_ELEM, arr, dst,
                       tid, lane, wid, sred);
            __syncthreads();
            continue;
        }

        const unsigned* cand = wsu + (arr ? CANDB_OFF : CANDA_OFF) + (size_t)s * CAP;
        for (int i = tid; i < n; i += 256) L[i] = cand[i];
        if (tid == 0) { shK = TOPK; shR = 0; shResolved = 0; }
        __syncthreads();

        unsigned prefix = 0u, himask = 0u;
        const int shifts[4] = {22, 12, 2, 0};
        const unsigned bmask[4] = {1023u, 1023u, 1023u, 3u};
#pragma unroll
        for (int lev = 0; lev < 4; ++lev) {
            if (!shResolved) {  // block-uniform
                const int shift = shifts[lev];
                const unsigned bm = bmask[lev];
                for (int i = tid; i < BINS; i += 256) hist[i] = 0;
                __syncthreads();
                for (int i = tid; i < n; i += 256) {
                    unsigned u = L[i];
                    if ((u & himask) == prefix) atomicAdd(&hist[(u >> shift) & bm], 1);
                }
                __syncthreads();
                const int K = shK;
                int c0 = hist[4 * tid], c1 = hist[4 * tid + 1], c2 = hist[4 * tid + 2], c3 = hist[4 * tid + 3];
                int suf = c0 + c1 + c2 + c3;
#pragma unroll
                for (int off = 1; off < 64; off <<= 1) {
                    int v = __shfl_down(suf, off, 64);
                    if (lane + off < 64) suf += v;
                }
                if (lane == 0) wtot[wid] = suf;
                if (tid == 0) shBt = -1;
                __syncthreads();
                int S = suf;
                for (int w = wid + 1; w < 4; ++w) S += wtot[w];
                {
                    int sfx = S;
                    int cc[4] = {c0, c1, c2, c3};
#pragma unroll
                    for (int q = 0; q < 4; ++q) {
                        int cnt = cc[q];
                        if (sfx >= K && sfx - cnt < K) { shBt = 4 * tid + q; shChi = sfx - cnt; shCntBt = cnt; }
                        sfx -= cnt;
                    }
                }
                __syncthreads();
                const int bt = shBt;
                if (bt < 0) {
                    // fewer than K active values (unreachable when n >= 30 at lev 0)
                    for (int i = tid; i < n; i += 256) {
                        unsigned u = L[i];
                        if ((u & himask) == prefix) {
                            int pos = atomicAdd(&shR, 1);
                            if (pos < TOPK) R[pos] = u;
                        }
                    }
                    __syncthreads();
                    if (tid == 0) shResolved = 1;
                    __syncthreads();
                } else {
                    const int chi = shChi, cntbt = shCntBt;
                    const int Knew = K - chi;
                    const int finish = (cntbt == Knew) ? 1 : 0;
                    for (int i = tid; i < n; i += 256) {
                        unsigned u = L[i];
                        if ((u & himask) == prefix) {
                            int b_ = (int)((u >> shift) & bm);
                            if (b_ > bt || (finish && b_ == bt)) {
                                int pos = atomicAdd(&shR, 1);
                                R[pos] = u;
                            }
                        }
                    }
                    __syncthreads();
                    if (finish) {
                        if (tid == 0) shResolved = 1;
                    } else if (lev == 3) {
                        // exact-value tie at boundary: append Knew copies
                        unsigned ustar = prefix | (unsigned)bt;
                        if (tid < Knew) { int pos = atomicAdd(&shR, 1); R[pos] = ustar; }
                        if (tid == 0) shResolved = 1;
                    } else {
                        if (tid == 0) shK = Knew;
                        prefix |= ((unsigned)bt << shift);
                        himask |= (bm << shift);
                    }
                    __syncthreads();
                }
            }
        }
        __syncthreads();
        // deterministic rank-sort of the 30 winners (kills atomic-order
        // nondeterminism in the hinge-sum rounding)
        if (tid < TOPK) {
            unsigned key = R[tid];
            int rank = 0;
#pragma unroll
            for (int j = 0; j < TOPK; ++j) {
                unsigned kj = R[j];
                rank += (kj > key) || (kj == key && j < tid);
            }
            dst[rank] = invord_sigmoid(key);
        }
        __syncthreads();
    }

    // 30x30 hinge sum
    float rs = 0.f;
    for (int pch = tid; pch < TOPK * TOPK; pch += 256) {
        int i = pch / TOPK, j = pch - i * TOPK;
        float th = ntop[i] - (1.0f - pv[j]) + 0.3f;
        rs += fmaxf(th, 0.0f);
    }
    for (int off = 32; off; off >>= 1) rs += __shfl_xor(rs, off, 64);
    if (lane == 0) fred[4 + wid] = rs;
    __syncthreads();

    if (tid == 0) {
        float SP = fred[0], ST = fred[1], SPT = fred[2];
        float RS = fred[4] + fred[5] + fred[6] + fred[7];
        const float Nf = (float)N_ELEM;
        float dice1 = 1.0f - 2.0f * SPT / (SP + ST + 1e-5f);
        float dice0 = 1.0f - 2.0f * (Nf - SP - ST + SPT) / ((Nf - SP) + (Nf - ST) + 1e-5f);
        float* samp = wsf + SAMP_OFF + s * 2;
        samp[0] = dice0 + dice1;
        samp[1] = RS;
    }
    __threadfence();
    if (tid == 0) shDone = atomicAdd((int*)&wsu[DONE_OFF], 1);
    __syncthreads();
    if (shDone == B_SAMPLES - 1) {
        __threadfence();
        float d = 0.f, r = 0.f;
        if (tid < B_SAMPLES) {
            d = wsf[SAMP_OFF + tid * 2 + 0];
            r = wsf[SAMP_OFF + tid * 2 + 1];
        }
        for (int off = 32; off; off >>= 1) {
            d += __shfl_xor(d, off, 64);
            r += __shfl_xor(r, off, 64);
        }
        if (tid == 0) {
            out[0] = d * (1.0f / (2.0f * B_SAMPLES));
            out[1] = r * (1.0f / (B_SAMPLES * TOPK * TOPK));
        }
    }
}

extern "C" void kernel_launch(void* const* d_in, const int* in_sizes, int n_in,
                              void* d_out, int out_size, void* d_ws, size_t ws_size,
                              hipStream_t stream) {
    (void)in_sizes; (void)n_in; (void)out_size; (void)ws_size;
    const float* pred = (const float*)d_in[0];
    const float* tgt  = (const float*)d_in[1];
    float* wsf = (float*)d_ws;
    float* out = (float*)d_out;

    // zero candidate counters + done flag (ws is poisoned 0xAA each launch)
    hipMemsetAsync((char*)d_ws + (size_t)CTR_OFF * 4, 0, 65 * 4, stream);
    passA<<<B_SAMPLES * BLOCKS_PER_S, 256, 0, stream>>>(pred, tgt, wsf);
    passB<<<B_SAMPLES, 256, 0, stream>>>(pred, tgt, wsf, out);
}

// Round 7
// 146.180 us; speedup vs baseline: 2.6222x; 2.6222x over previous
//
#include <hip/hip_runtime.h>

// Fusin_Dice_rank: fused 2-ch softmax + dice + top-30 rank hinge.
// Keys: order-preserving u32 ord(d), d = x1-x0 (monotone with p=sigmoid(d)).
// t binary -> element feeds exactly ONE top-k problem:
//   A (t==0): key o=ordf(d);  B (t==1): key ~o = ordf(-d).
// passA: streaming; dice partials; static-threshold filter (d>=3.5) with
//   PER-BLOCK LDS compaction (no global atomics!) -> per-block candidate
//   lists (<=64) + counts.
// passB (32 blocks): wave-parallel gather + wave-local exact binary-search
//   top-30 (no barriers) for A (wave1) and B (wave2), dice (wave0), hinge,
//   sample finalize; exact whole-sample fallback if filter under/overflows
//   (unreachable on bench data). Last finishing block reduces 32 samples.

#define N_ELEM (512 * 512)
#define B_SAMPLES 32
#define CHUNK 4096
#define BLOCKS_PER_S 64
#define TOPK 30
#define CAP_B 64            // per-block candidate capacity (mean ~13.7, >10 sigma)
#define LCAP (BLOCKS_PER_S * CAP_B)  // 4096: per-sample LDS gather capacity
// ordf(3.5f): 3.5f = 0x40600000, positive -> | 0x80000000
#define THR_KEY 0xC0600000u

// ws layout in 4-byte units
#define PART_OFF 0                                         // [32][64][3] f32
#define CNTA_OFF (PART_OFF + B_SAMPLES * BLOCKS_PER_S * 3) // [2048] u32
#define CNTB_OFF (CNTA_OFF + B_SAMPLES * BLOCKS_PER_S)     // [2048] u32
#define CANDA_OFF (CNTB_OFF + B_SAMPLES * BLOCKS_PER_S)    // [2048][64] u32
#define CANDB_OFF (CANDA_OFF + B_SAMPLES * BLOCKS_PER_S * CAP_B)
#define SAMP_OFF (CANDB_OFF + B_SAMPLES * BLOCKS_PER_S * CAP_B) // [32][2] f32
#define DONE_OFF (SAMP_OFF + B_SAMPLES * 2)                // [1] u32

__device__ __forceinline__ unsigned ordf(float f) {
    unsigned u = __float_as_uint(f);
    return (u & 0x80000000u) ? ~u : (u | 0x80000000u);
}

__device__ __forceinline__ float invord_sigmoid(unsigned u) {
    if (u == 0u) return 0.0f;
    unsigned b = (u & 0x80000000u) ? (u ^ 0x80000000u) : ~u;
    float f = __uint_as_float(b);
    return 1.0f / (1.0f + __expf(-f));
}

__device__ __forceinline__ unsigned long long shflxor_u64(unsigned long long v, int off) {
    unsigned lo = (unsigned)v, hi = (unsigned)(v >> 32);
    lo = __shfl_xor(lo, off, 64);
    hi = __shfl_xor(hi, off, 64);
    return ((unsigned long long)hi << 32) | lo;
}

__global__ __launch_bounds__(256) void passA(const float* __restrict__ pred,
                                             const float* __restrict__ tgt,
                                             float* __restrict__ wsf) {
    unsigned* wsu = (unsigned*)wsf;
    const int s = blockIdx.x >> 6, c = blockIdx.x & 63;
    const int tid = threadIdx.x, lane = tid & 63, wid = tid >> 6;

    __shared__ float red[12];
    __shared__ int shCntA, shCntB;
    __shared__ unsigned LA_s[CAP_B], LB_s[CAP_B];

    if (tid == 0) { shCntA = 0; shCntB = 0; }
    if (blockIdx.x == 0 && tid == 0) wsu[DONE_OFF] = 0u;  // consumed only by passB

    const float* x0p = pred + (size_t)s * 2 * N_ELEM + (size_t)c * CHUNK;
    const float* x1p = x0p + N_ELEM;
    const float* tp  = tgt + (size_t)s * N_ELEM + (size_t)c * CHUNK;

    unsigned o[16];
    unsigned tmask = 0u;
    float sp = 0.f, spt = 0.f;

#pragma unroll
    for (int j = 0; j < 4; ++j) {
        float4 X0 = ((const float4*)x0p)[j * 256 + tid];
        float4 X1 = ((const float4*)x1p)[j * 256 + tid];
        float4 T  = ((const float4*)tp )[j * 256 + tid];
#define PROC(q, xx0, xx1, tt)                                  \
        {                                                      \
            float d = (xx1) - (xx0);                           \
            float p = 1.0f / (1.0f + __expf(-d));              \
            sp += p; spt = fmaf(p, (tt), spt);                 \
            o[j * 4 + (q)] = ordf(d);                          \
            if ((tt) != 0.0f) tmask |= 1u << (j * 4 + (q));    \
        }
        PROC(0, X0.x, X1.x, T.x)
        PROC(1, X0.y, X1.y, T.y)
        PROC(2, X0.z, X1.z, T.z)
        PROC(3, X0.w, X1.w, T.w)
#undef PROC
    }
    float st = (float)__popc(tmask);

    // dice partial sums (wave reduce)
    for (int off = 32; off; off >>= 1) {
        sp  += __shfl_xor(sp, off, 64);
        st  += __shfl_xor(st, off, 64);
        spt += __shfl_xor(spt, off, 64);
    }
    if (lane == 0) { red[wid * 3] = sp; red[wid * 3 + 1] = st; red[wid * 3 + 2] = spt; }
    __syncthreads();  // counters zeroed + red visible

    // static-threshold emit to per-block LDS buffers (~27 passers/block)
#pragma unroll
    for (int e = 0; e < 16; ++e) {
        unsigned key = o[e];
        if ((tmask >> e) & 1u) {
            unsigned kb = ~key;                        // == ordf(-d)
            if (kb >= THR_KEY) {
                int pos = atomicAdd(&shCntB, 1);
                if (pos < CAP_B) LB_s[pos] = kb;
            }
        } else {
            if (key >= THR_KEY) {
                int pos = atomicAdd(&shCntA, 1);
                if (pos < CAP_B) LA_s[pos] = key;
            }
        }
    }
    __syncthreads();

    const int blk = s * BLOCKS_PER_S + c;
    const int nA = shCntA, nB = shCntB;
    if (tid == 0) {
        float a = 0.f, b = 0.f, cc = 0.f;
#pragma unroll
        for (int w = 0; w < 4; ++w) { a += red[w * 3]; b += red[w * 3 + 1]; cc += red[w * 3 + 2]; }
        float* part = wsf + PART_OFF + (size_t)blk * 3;
        part[0] = a; part[1] = b; part[2] = cc;
        wsu[CNTA_OFF + blk] = (unsigned)nA;   // raw count: >CAP_B flags fallback
        wsu[CNTB_OFF + blk] = (unsigned)nB;
    }
    if (tid < CAP_B) {
        if (tid < min(nA, CAP_B)) wsu[CANDA_OFF + (size_t)blk * CAP_B + tid] = LA_s[tid];
        if (tid < min(nB, CAP_B)) wsu[CANDB_OFF + (size_t)blk * CAP_B + tid] = LB_s[tid];
    }
}

// Exact top-30 fallback: 30 rounds of block argmax over the full sample.
// Only if the threshold filter failed (unreachable on bench data).
__device__ void fallback30(const float* __restrict__ x0p, const float* __restrict__ x1p,
                           const float* __restrict__ tp, int isB, float* dst,
                           int tid, int lane, int wid, unsigned long long* sred) {
    unsigned long long prev = ~0ull;
    for (int r = 0; r < TOPK; ++r) {
        unsigned long long best = 0ull;
        for (int e = tid; e < N_ELEM; e += 256) {
            float d = x1p[e] - x0p[e];
            float t = tp[e];
            unsigned key;
            if (isB) key = (t != 0.0f) ? ordf(-d) : 0u;
            else     key = (t == 0.0f) ? ordf(d) : 0u;
            unsigned long long pk = ((unsigned long long)key << 18) | (unsigned)e;
            if (pk < prev && pk > best) best = pk;
        }
        for (int off = 32; off; off >>= 1) {
            unsigned long long v = shflxor_u64(best, off);
            if (v > best) best = v;
        }
        if (lane == 0) sred[wid] = best;
        __syncthreads();
        unsigned long long b0 = sred[0];
#pragma unroll
        for (int w = 1; w < 4; ++w) if (sred[w] > b0) b0 = sred[w];
        __syncthreads();
        if (tid == 0) dst[r] = invord_sigmoid((unsigned)(b0 >> 18));
        prev = b0;
    }
}

// Wave-local exact top-30 over one sample's candidate lists. No barriers.
// flag: >=0 ok, -1 -> caller must run fallback.
__device__ void wave_select(const unsigned* __restrict__ candG,  // [64][CAP_B]
                            const unsigned* __restrict__ cntG,   // [64]
                            unsigned* lbuf,                      // LDS [LCAP]
                            unsigned* rbuf,                      // LDS [TOPK]
                            int* rcnt,                           // LDS, pre-zeroed
                            int* flag,                           // LDS
                            float* dst,                          // [TOPK]
                            int lane) {
    int cvr = (int)cntG[lane];
    int cv = min(cvr, CAP_B);
    unsigned long long ovb = __ballot(cvr > CAP_B);
    // inclusive scan of cv
    int pe = cv;
#pragma unroll
    for (int off = 1; off < 64; off <<= 1) {
        int v = __shfl_up(pe, off, 64);
        if (lane >= off) pe += v;
    }
    const int n = __shfl(pe, 63, 64);
    const int pf = pe - cv;
    if (n < TOPK || ovb != 0ull) {
        if (lane == 0) *flag = -1;
        return;
    }
    if (lane == 0) *flag = n;
    // gather into LDS (same-wave LDS ordering guarantees visibility below)
    for (int i = 0; i < cv; ++i) lbuf[pf + i] = candG[lane * CAP_B + i];
    // wave max to tighten the search range
    unsigned mx = 0u;
    for (int i = lane; i < n; i += 64) mx = max(mx, lbuf[i]);
#pragma unroll
    for (int off = 32; off; off >>= 1) mx = max(mx, (unsigned)__shfl_xor((int)mx, off, 64));
    // binary search: largest lo with count(key >= lo) >= TOPK
    unsigned lo = THR_KEY, hi = mx + 1u;
    while (hi - lo > 1u) {
        unsigned mid = lo + ((hi - lo) >> 1);
        int cnum = 0;
        for (int i = lane; i < n; i += 64) cnum += (lbuf[i] >= mid);
#pragma unroll
        for (int off = 32; off; off >>= 1) cnum += __shfl_xor(cnum, off, 64);
        if (cnum >= TOPK) lo = mid; else hi = mid;
    }
    // ch = count(key > lo) < TOPK; emit those, pad with copies of lo
    int ch = 0;
    for (int i = lane; i < n; i += 64) ch += (lbuf[i] > lo);
#pragma unroll
    for (int off = 32; off; off >>= 1) ch += __shfl_xor(ch, off, 64);
    for (int i = lane; i < n; i += 64) {
        unsigned k = lbuf[i];
        if (k > lo) { int pos = atomicAdd(rcnt, 1); rbuf[pos] = k; }
    }
    if (lane < TOPK - ch) rbuf[ch + lane] = lo;
    // deterministic rank-sort -> dst descending
    if (lane < TOPK) {
        unsigned key = rbuf[lane];
        int rank = 0;
#pragma unroll
        for (int j = 0; j < TOPK; ++j) {
            unsigned kj = rbuf[j];
            rank += (kj > key) || (kj == key && j < lane);
        }
        dst[rank] = invord_sigmoid(key);
    }
}

__global__ __launch_bounds__(256) void passB(const float* __restrict__ pred,
                                             const float* __restrict__ tgt,
                                             float* __restrict__ wsf,
                                             float* __restrict__ out) {
    unsigned* wsu = (unsigned*)wsf;
    const int s = blockIdx.x;
    const int tid = threadIdx.x, lane = tid & 63, wid = tid >> 6;

    __shared__ unsigned LA2[LCAP], LB2[LCAP];   // 32 KB
    __shared__ unsigned RA[TOPK], RB[TOPK];
    __shared__ int rcA, rcB, flagA, flagB, shDone;
    __shared__ float ntop[TOPK], pv[TOPK], fred[8];
    __shared__ unsigned long long sred[4];

    if (tid == 0) { rcA = 0; rcB = 0; flagA = 0; flagB = 0; }
    __syncthreads();

    if (wid == 0) {
        // dice sums over 64 chunk partials
        const float* part = wsf + PART_OFF + (size_t)(s * BLOCKS_PER_S + lane) * 3;
        float sp = part[0], st = part[1], spt = part[2];
        for (int off = 32; off; off >>= 1) {
            sp  += __shfl_xor(sp, off, 64);
            st  += __shfl_xor(st, off, 64);
            spt += __shfl_xor(spt, off, 64);
        }
        if (lane == 0) { fred[0] = sp; fred[1] = st; fred[2] = spt; }
    } else if (wid == 1) {
        wave_select(wsu + CANDA_OFF + (size_t)s * BLOCKS_PER_S * CAP_B,
                    wsu + CNTA_OFF + s * BLOCKS_PER_S,
                    LA2, RA, &rcA, &flagA, ntop, lane);
    } else if (wid == 2) {
        wave_select(wsu + CANDB_OFF + (size_t)s * BLOCKS_PER_S * CAP_B,
                    wsu + CNTB_OFF + s * BLOCKS_PER_S,
                    LB2, RB, &rcB, &flagB, pv, lane);
    }
    __syncthreads();

    // block-uniform fallbacks (unreachable on bench data)
    if (flagA < 0) {
        const float* x0p = pred + (size_t)s * 2 * N_ELEM;
        fallback30(x0p, x0p + N_ELEM, tgt + (size_t)s * N_ELEM, 0, ntop, tid, lane, wid, sred);
    }
    if (flagB < 0) {
        const float* x0p = pred + (size_t)s * 2 * N_ELEM;
        fallback30(x0p, x0p + N_ELEM, tgt + (size_t)s * N_ELEM, 1, pv, tid, lane, wid, sred);
    }
    __syncthreads();

    // 30x30 hinge sum
    float rs = 0.f;
    for (int pch = tid; pch < TOPK * TOPK; pch += 256) {
        int i = pch / TOPK, j = pch - i * TOPK;
        float th = ntop[i] - (1.0f - pv[j]) + 0.3f;
        rs += fmaxf(th, 0.0f);
    }
    for (int off = 32; off; off >>= 1) rs += __shfl_xor(rs, off, 64);
    if (lane == 0) fred[4 + wid] = rs;
    __syncthreads();

    if (tid == 0) {
        float SP = fred[0], ST = fred[1], SPT = fred[2];
        float RS = fred[4] + fred[5] + fred[6] + fred[7];
        const float Nf = (float)N_ELEM;
        float dice1 = 1.0f - 2.0f * SPT / (SP + ST + 1e-5f);
        float dice0 = 1.0f - 2.0f * (Nf - SP - ST + SPT) / ((Nf - SP) + (Nf - ST) + 1e-5f);
        float* samp = wsf + SAMP_OFF + s * 2;
        samp[0] = dice0 + dice1;
        samp[1] = RS;
    }
    __threadfence();
    if (tid == 0) shDone = atomicAdd((int*)&wsu[DONE_OFF], 1);
    __syncthreads();
    if (shDone == B_SAMPLES - 1) {
        __threadfence();
        float d = 0.f, r = 0.f;
        if (tid < B_SAMPLES) {
            d = wsf[SAMP_OFF + tid * 2 + 0];
            r = wsf[SAMP_OFF + tid * 2 + 1];
        }
        for (int off = 32; off; off >>= 1) {
            d += __shfl_xor(d, off, 64);
            r += __shfl_xor(r, off, 64);
        }
        if (tid == 0) {
            out[0] = d * (1.0f / (2.0f * B_SAMPLES));
            out[1] = r * (1.0f / (B_SAMPLES * TOPK * TOPK));
        }
    }
}

extern "C" void kernel_launch(void* const* d_in, const int* in_sizes, int n_in,
                              void* d_out, int out_size, void* d_ws, size_t ws_size,
                              hipStream_t stream) {
    (void)in_sizes; (void)n_in; (void)out_size; (void)ws_size;
    const float* pred = (const float*)d_in[0];
    const float* tgt  = (const float*)d_in[1];
    float* wsf = (float*)d_ws;
    float* out = (float*)d_out;

    passA<<<B_SAMPLES * BLOCKS_PER_S, 256, 0, stream>>>(pred, tgt, wsf);
    passB<<<B_SAMPLES, 256, 0, stream>>>(pred, tgt, wsf, out);
}